// Round 6
// 212.190 us; speedup vs baseline: 1.0236x; 1.0236x over previous
//
#include <hip/hip_runtime.h>
#include <hip/hip_bf16.h>
#include <math.h>

// STFT: inputs [64, 262144] f32, frame_length=8, frame_step=4, periodic Hann.
// num_frames = (262144-8)/4 + 1 = 65535, bins = 5.
// out = concat(magnitude[64,5,65535], phase[64,5,65535]) flat f32.

#define B 64
#define T 262144
#define NUM_FRAMES 65535
#define BINS 5

__global__ __launch_bounds__(256) void stft_kernel(const float* __restrict__ in,
                                                   float* __restrict__ out) {
    const int f = blockIdx.x * 256 + threadIdx.x;   // frame index
    const int b = blockIdx.y;                        // batch row
    if (f >= NUM_FRAMES) return;

    // Frame starts at sample f*4; 8 samples = two aligned float4 loads.
    const float4* p = (const float4*)(in + (size_t)b * T + (size_t)f * 4);
    const float4 lo = p[0];
    const float4 hi = p[1];

    // Periodic Hann window, w[0] = 0 (sample 0 drops out).
    const float w1 = 0.14644660940672624f;  // 0.5 - 0.5*cos(pi/4)
    const float w3 = 0.85355339059327376f;  // 0.5 - 0.5*cos(3pi/4)
    const float x1 = lo.y * w1;
    const float x2 = lo.z * 0.5f;
    const float x3 = lo.w * w3;
    const float x4 = hi.x;          // w4 = 1
    const float x5 = hi.y * w3;
    const float x6 = hi.z * 0.5f;
    const float x7 = hi.w * w1;

    const float c = 0.70710678118654752f;   // sqrt(2)/2
    const float s1  = x1 - x3 - x5 + x7;
    const float s2  = x1 + x3 - x5 - x7;
    const float d26 = x2 - x6;

    // X[k] = sum_n x[n] e^{-2pi i k n / 8}
    const float re0 = x1 + x2 + x3 + x4 + x5 + x6 + x7;
    const float re1 = -x4 + c * s1;
    const float im1 = -c * s2 - d26;
    const float re2 = -x2 + x4 - x6;
    const float im2 = -(x1 - x3 + x5 - x7);
    const float re3 = -x4 - c * s1;
    const float im3 = -c * s2 + d26;
    const float re4 = -x1 + x2 - x3 + x4 - x5 + x6 - x7;

    // Output layout: mag[b][k][f] then phase[b][k][f].
    const size_t plane = (size_t)NUM_FRAMES;
    float* mag = out + ((size_t)b * BINS) * plane + f;
    float* ph  = mag + (size_t)B * BINS * plane;

    mag[0 * plane] = fabsf(re0);
    mag[1 * plane] = sqrtf(re1 * re1 + im1 * im1);
    mag[2 * plane] = sqrtf(re2 * re2 + im2 * im2);
    mag[3 * plane] = sqrtf(re3 * re3 + im3 * im3);
    mag[4 * plane] = fabsf(re4);

    ph[0 * plane] = atan2f(0.0f, re0);
    ph[1 * plane] = atan2f(im1, re1);
    ph[2 * plane] = atan2f(im2, re2);
    ph[3 * plane] = atan2f(im3, re3);
    ph[4 * plane] = atan2f(0.0f, re4);
}

extern "C" void kernel_launch(void* const* d_in, const int* in_sizes, int n_in,
                              void* d_out, int out_size, void* d_ws, size_t ws_size,
                              hipStream_t stream) {
    (void)in_sizes; (void)n_in; (void)d_ws; (void)ws_size; (void)out_size;
    const float* in = (const float*)d_in[0];
    float* out = (float*)d_out;

    dim3 block(256);
    dim3 grid((NUM_FRAMES + 255) / 256, B);   // 256 x 64
    stft_kernel<<<grid, block, 0, stream>>>(in, out);
}